// Round 1
// baseline (1037.561 us; speedup 1.0000x reference)
//
#include <hip/hip_runtime.h>
#include <math.h>

#define NB 1000      // graphs
#define NN 100       // nodes per graph
#define EPG 1000     // edges per graph
#define FIN 14
#define HD 128
#define KP1 80
#define KP2 64

// ---------------- Kernel A: conv1 + pool1 + readout1 ----------------
__global__ __launch_bounds__(256) void conv1_pool1(
    const float* __restrict__ x, const int* __restrict__ ei,
    const float* __restrict__ Wrel1, const float* __restrict__ Wroot1,
    const float* __restrict__ b1, const float* __restrict__ p1,
    float* __restrict__ h1p, float* __restrict__ m1, float* __restrict__ x1)
{
    __shared__ float xg[NN * FIN];
    __shared__ float agg[NN * FIN];
    __shared__ float h[NN * HD];
    __shared__ float sc[NN];
    __shared__ float mk[NN];
    __shared__ float invn;

    const int tid = threadIdx.x;
    const int g = blockIdx.x;
    const int bn = g * NN;
    const int* srcp = ei + g * EPG;
    const int* dstp = ei + NB * EPG + g * EPG;

    for (int t = tid; t < NN * FIN; t += 256) {
        xg[t] = x[bn * FIN + t];
        agg[t] = 0.f;
    }
    if (tid == 0) {
        float ns = 0.f;
        for (int k = 0; k < HD; ++k) { float v = p1[k]; ns += v * v; }
        invn = rsqrtf(ns);
    }
    __syncthreads();

    // edge aggregation (feature dim = 14) via LDS atomics
    for (int e = tid; e < EPG; e += 256) {
        int sl = srcp[e] - bn;
        int dl = dstp[e] - bn;
        for (int f = 0; f < FIN; ++f)
            atomicAdd(&agg[dl * FIN + f], xg[sl * FIN + f]);
    }
    __syncthreads();

    // h1 = relu(agg @ Wrel1 + x @ Wroot1 + b1)
    for (int o = tid; o < NN * HD; o += 256) {
        int i = o >> 7, j = o & 127;
        float s = b1[j];
        for (int k = 0; k < FIN; ++k)
            s += agg[i * FIN + k] * Wrel1[k * HD + j]
               + xg[i * FIN + k] * Wroot1[k * HD + j];
        h[o] = fmaxf(s, 0.f);
    }
    __syncthreads();

    // scores: tanh(h . p1 / ||p1||), skewed k to avoid bank conflicts
    if (tid < NN) {
        float d = 0.f;
        for (int k = 0; k < HD; ++k) {
            int kk = (k + tid) & 127;
            d += h[tid * HD + kk] * p1[kk];
        }
        sc[tid] = tanhf(d * invn);
    }
    __syncthreads();

    // rank-count top-K1
    if (tid < NN) {
        float si = sc[tid];
        int cnt = 0;
        for (int j2 = 0; j2 < NN; ++j2) cnt += (sc[j2] > si) ? 1 : 0;
        float m = (cnt < KP1) ? 1.f : 0.f;
        mk[tid] = m;
        m1[bn + tid] = m;
    }
    __syncthreads();

    // scale h by s*mask, write pooled h to global
    for (int o = tid; o < NN * HD; o += 256) {
        int i = o >> 7;
        float v = h[o] * sc[i] * mk[i];
        h[o] = v;
        h1p[bn * HD + o] = v;
    }
    __syncthreads();

    // readout1: mean/K1 over all (dead zeroed) ; max over alive
    if (tid < HD) {
        float mean = 0.f, mx = -1e30f;
        for (int i = 0; i < NN; ++i) {
            float v = h[i * HD + tid];
            mean += v;
            if (mk[i] > 0.f && v > mx) mx = v;
        }
        x1[g * (2 * HD) + tid] = mean / (float)KP1;
        x1[g * (2 * HD) + HD + tid] = mx;
    }
}

// ------------- Kernel B: conv2 + pool2 + readout2 + MLP -------------
__global__ __launch_bounds__(256) void conv2_pool2_mlp(
    const int* __restrict__ ei, const float* __restrict__ h1p,
    const float* __restrict__ m1, const float* __restrict__ x1,
    const float* __restrict__ Wrel2, const float* __restrict__ Wroot2,
    const float* __restrict__ b2, const float* __restrict__ p2,
    const float* __restrict__ l1w, const float* __restrict__ l1b,
    const float* __restrict__ l2w, const float* __restrict__ l2b,
    const float* __restrict__ l3w, const float* __restrict__ l3b,
    float* __restrict__ out)
{
    __shared__ float A[NN * HD];   // agg2, then h1p, then h2 (in sequence)
    __shared__ float m1s[NN];
    __shared__ float sc2[NN];
    __shared__ float mk2[NN];
    __shared__ float zsh[2 * HD];
    __shared__ float z1[HD];
    __shared__ float z2[32];
    __shared__ float invn2;

    const int tid = threadIdx.x;
    const int g = blockIdx.x;
    const int bn = g * NN;
    const int* srcp = ei + g * EPG;
    const int* dstp = ei + NB * EPG + g * EPG;

    if (tid < NN) m1s[tid] = m1[bn + tid];
    if (tid == 255) {
        float ns = 0.f;
        for (int k = 0; k < HD; ++k) { float v = p2[k]; ns += v * v; }
        invn2 = rsqrtf(ns);
    }
    for (int t = tid; t < NN * HD; t += 256) A[t] = 0.f;
    __syncthreads();

    // masked edge aggregation: lane owns a fixed feature column
    {
        const int j = tid & 127;
        for (int e = (tid >> 7); e < EPG; e += 2) {
            int sl = srcp[e] - bn;
            int dl = dstp[e] - bn;
            if (m1s[sl] > 0.f && m1s[dl] > 0.f)
                atomicAdd(&A[dl * HD + j], h1p[(bn + sl) * HD + j]);
        }
    }
    __syncthreads();

    // GEMM: h2 = relu(agg2 @ Wrel2 + h1p @ Wroot2 + b2)
    // thread tile: 13 rows x 4 cols
    const int tr = tid >> 5;        // 0..7
    const int tc = tid & 31;        // 0..31
    const int i0 = tr * 13;
    const int j0 = tc * 4;

    float acc[13][4];
#pragma unroll
    for (int r = 0; r < 13; ++r) {
        acc[r][0] = 0.f; acc[r][1] = 0.f; acc[r][2] = 0.f; acc[r][3] = 0.f;
    }

    const float4* Wrel2v = (const float4*)Wrel2;
    const float4* Wroot2v = (const float4*)Wroot2;

    // pass 1: agg2 @ Wrel2  (A holds agg2)
    for (int k = 0; k < HD; ++k) {
        float4 w = Wrel2v[k * 32 + tc];
#pragma unroll
        for (int r = 0; r < 13; ++r) {
            if (i0 + r < NN) {
                float a = A[(i0 + r) * HD + k];
                acc[r][0] += a * w.x; acc[r][1] += a * w.y;
                acc[r][2] += a * w.z; acc[r][3] += a * w.w;
            }
        }
    }
    __syncthreads();

    // reload A with h1p
    for (int t = tid; t < NN * HD; t += 256) A[t] = h1p[bn * HD + t];
    __syncthreads();

    // pass 2: h1p @ Wroot2
    for (int k = 0; k < HD; ++k) {
        float4 w = Wroot2v[k * 32 + tc];
#pragma unroll
        for (int r = 0; r < 13; ++r) {
            if (i0 + r < NN) {
                float a = A[(i0 + r) * HD + k];
                acc[r][0] += a * w.x; acc[r][1] += a * w.y;
                acc[r][2] += a * w.z; acc[r][3] += a * w.w;
            }
        }
    }
    __syncthreads();

    // write h2 = relu(acc + b2) back into A
    {
        float b0 = b2[j0], bb1 = b2[j0 + 1], bb2 = b2[j0 + 2], bb3 = b2[j0 + 3];
#pragma unroll
        for (int r = 0; r < 13; ++r) {
            if (i0 + r < NN) {
                A[(i0 + r) * HD + j0 + 0] = fmaxf(acc[r][0] + b0, 0.f);
                A[(i0 + r) * HD + j0 + 1] = fmaxf(acc[r][1] + bb1, 0.f);
                A[(i0 + r) * HD + j0 + 2] = fmaxf(acc[r][2] + bb2, 0.f);
                A[(i0 + r) * HD + j0 + 3] = fmaxf(acc[r][3] + bb3, 0.f);
            }
        }
    }
    __syncthreads();

    // scores2: only alive nodes; dead -> -1e30
    if (tid < NN) {
        if (m1s[tid] > 0.f) {
            float d = 0.f;
            for (int k = 0; k < HD; ++k) {
                int kk = (k + tid) & 127;
                d += A[tid * HD + kk] * p2[kk];
            }
            sc2[tid] = tanhf(d * invn2);
        } else {
            sc2[tid] = -1e30f;
        }
    }
    __syncthreads();

    // rank-count top-K2 among alive
    if (tid < NN) {
        float si = sc2[tid];
        int cnt = 0;
        for (int j2 = 0; j2 < NN; ++j2) cnt += (sc2[j2] > si) ? 1 : 0;
        mk2[tid] = (m1s[tid] > 0.f && cnt < KP2) ? 1.f : 0.f;
    }
    __syncthreads();

    // scale h2 by s2*mask2
    for (int o = tid; o < NN * HD; o += 256) {
        int i = o >> 7;
        A[o] *= sc2[i] * mk2[i];
    }
    __syncthreads();

    // readout2 + z = x1 + x2
    if (tid < HD) {
        float mean = 0.f, mx = -1e30f;
        for (int i = 0; i < NN; ++i) {
            float v = A[i * HD + tid];
            mean += v;
            if (mk2[i] > 0.f && v > mx) mx = v;
        }
        zsh[tid] = x1[g * 256 + tid] + mean / (float)KP2;
        zsh[HD + tid] = x1[g * 256 + HD + tid] + mx;
    }
    __syncthreads();

    // MLP layer 1: 256 -> 128, relu
    if (tid < HD) {
        float a = l1b[tid];
        for (int k = 0; k < 2 * HD; ++k) a += zsh[k] * l1w[k * HD + tid];
        z1[tid] = fmaxf(a, 0.f);
    }
    __syncthreads();

    // MLP layer 2: 128 -> 32, relu
    if (tid < 32) {
        float a = l2b[tid];
        for (int k = 0; k < HD; ++k) a += z1[k] * l2w[k * 32 + tid];
        z2[tid] = fmaxf(a, 0.f);
    }
    __syncthreads();

    // MLP layer 3: 32 -> 2, log_softmax
    if (tid == 0) {
        float o0 = l3b[0], o1 = l3b[1];
        for (int k = 0; k < 32; ++k) {
            o0 += z2[k] * l3w[k * 2 + 0];
            o1 += z2[k] * l3w[k * 2 + 1];
        }
        float m = fmaxf(o0, o1);
        float l = m + logf(expf(o0 - m) + expf(o1 - m));
        out[g * 2 + 0] = o0 - l;
        out[g * 2 + 1] = o1 - l;
    }
}

extern "C" void kernel_launch(void* const* d_in, const int* in_sizes, int n_in,
                              void* d_out, int out_size, void* d_ws, size_t ws_size,
                              hipStream_t stream)
{
    const float* x      = (const float*)d_in[0];
    const int*   ei     = (const int*)d_in[1];
    const float* Wrel1  = (const float*)d_in[2];
    const float* Wroot1 = (const float*)d_in[3];
    const float* b1     = (const float*)d_in[4];
    const float* p1     = (const float*)d_in[5];
    const float* Wrel2  = (const float*)d_in[6];
    const float* Wroot2 = (const float*)d_in[7];
    const float* b2     = (const float*)d_in[8];
    const float* p2     = (const float*)d_in[9];
    const float* l1w    = (const float*)d_in[10];
    const float* l1b    = (const float*)d_in[11];
    const float* l2w    = (const float*)d_in[12];
    const float* l2b    = (const float*)d_in[13];
    const float* l3w    = (const float*)d_in[14];
    const float* l3b    = (const float*)d_in[15];

    float* out = (float*)d_out;
    float* ws  = (float*)d_ws;

    float* h1p = ws;                         // NB*NN*HD = 12,800,000 floats
    float* m1  = ws + 12800000;              // NB*NN    =    100,000 floats
    float* x1  = ws + 12900000;              // NB*2*HD  =    256,000 floats

    conv1_pool1<<<dim3(NB), dim3(256), 0, stream>>>(
        x, ei, Wrel1, Wroot1, b1, p1, h1p, m1, x1);

    conv2_pool2_mlp<<<dim3(NB), dim3(256), 0, stream>>>(
        ei, h1p, m1, x1, Wrel2, Wroot2, b2, p2,
        l1w, l1b, l2w, l2b, l3w, l3b, out);
}